// Round 15
// baseline (426.949 us; speedup 1.0000x reference)
//
#include <hip/hip_runtime.h>
#include <stdint.h>

#define NN 50000
#define EE 800000
#define IND 256
#define HD1 512   // layer1 concat width (4 heads x 128)
#define D2C 256   // layer2 width

// ---- two-level CSR sort geometry ----
#define NB1 782                 // buckets per layer (64 nodes each)
#define NB  (2 * NB1)           // 1564 buckets total
#define CH  16384               // edges per binning workgroup
#define WGN ((2 * EE + CH - 1) / CH)   // 98 workgroups
#define TOT (NB * WGN)          // 153272 hist entries
#define SB2 ((TOT + 255) / 256) // 599 scan blocks

// int8 fixed-point codec for h1 (values ~N(0,1); range +-6 never clips in practice)
// Stored BIASED (q+128) so decode is v_cvt_f32_ubyte0..3 (1 op/elem, not bfe+cvt).
// Bias correction folds into epilogue: sum w*(q-128)*Q_INV = (sum w*q - 128*l)*Q_INV.
#define Q_SCALE 21.166666f        // 127/6
#define Q_INV   0.047244094f      // 6/127

typedef float f32x4 __attribute__((ext_vector_type(4)));
typedef float f32x2 __attribute__((ext_vector_type(2)));
typedef __bf16 bf16x8 __attribute__((ext_vector_type(8)));

__device__ inline float bf2f(unsigned int u) {
    union { unsigned int i; float f; } c; c.i = u << 16; return c.f;
}
__device__ inline unsigned int f2bf(float f) {
    union { float f; unsigned int i; } c; c.f = f;
    unsigned int x = c.i;
    return (x + 0x7FFFu + ((x >> 16) & 1u)) >> 16;  // RNE
}
__device__ inline float loadf(const void* p, int idx, int isbf) {
    return isbf ? bf2f(((const unsigned short*)p)[idx]) : ((const float*)p)[idx];
}
// encode float -> biased uint8 byte (round-nearest, clamp +-127, +128 bias)
__device__ inline unsigned int f2q8(float v) {
    float t = fminf(fmaxf(v * Q_SCALE, -127.f), 127.f);
    int q = (int)rintf(t) + 128;
    return (unsigned int)q & 0xFFu;
}
// decode 8 biased-uint8 bytes -> 4x f32x2 (v_cvt_f32_ubyte; pairs feed pk-FMA)
__device__ inline void unpack8_u8_v2(uint2 q, f32x2* o) {
    o[0] = (f32x2){(float)(q.x & 0xFFu),         (float)((q.x >> 8) & 0xFFu)};
    o[1] = (f32x2){(float)((q.x >> 16) & 0xFFu), (float)(q.x >> 24)};
    o[2] = (f32x2){(float)(q.y & 0xFFu),         (float)((q.y >> 8) & 0xFFu)};
    o[3] = (f32x2){(float)((q.y >> 16) & 0xFFu), (float)(q.y >> 24)};
}
// async global->LDS 16B per lane: dest = lds_base + lane*16 (wave-uniform base)
__device__ inline void glds16(const unsigned short* g, unsigned short* lds_base) {
    __builtin_amdgcn_global_load_lds(
        (const __attribute__((address_space(1))) void*)g,
        (__attribute__((address_space(3))) void*)lds_base, 16, 0, 0);
}

// ---------------- dtype probe: external float tensors bf16 (flag=1) or fp32 (flag=0)
__global__ void probe_k(const unsigned int* __restrict__ w, int* __restrict__ flag) {
    __shared__ int red[256];
    int t = threadIdx.x;
    int ok = 0;
    for (int i = t; i < 4096; i += 256) {
        unsigned int v = w[i];
        unsigned int e0 = (v >> 7) & 0xffu;
        unsigned int e1 = (v >> 23) & 0xffu;
        ok += (e0 <= 133u) + (e1 <= 133u);
    }
    red[t] = ok;
    __syncthreads();
    for (int s = 128; s > 0; s >>= 1) {
        if (t < s) red[t] += red[t + s];
        __syncthreads();
    }
    if (t == 0) *flag = (red[0] >= 7782) ? 1 : 0;
}

// ---------------- feat -> bf16 (one-time conversion; copy if already bf16)
__global__ __launch_bounds__(256) void convert_k(
    const void* __restrict__ in, const int* __restrict__ flagp,
    unsigned short* __restrict__ out)
{
    int isbf = (*flagp != 0);
    size_t i = ((size_t)blockIdx.x * 256 + threadIdx.x) * 8;
    if (i >= (size_t)NN * IND) return;
    if (isbf) {
        *(uint4*)(out + i) = *(const uint4*)((const unsigned short*)in + i);
    } else {
        const float* f = (const float*)in + i;
        f32x4 p0 = *(const f32x4*)f;
        f32x4 p1 = *(const f32x4*)(f + 4);
        uint4 va;
        va.x = f2bf(p0.x) | (f2bf(p0.y) << 16);
        va.y = f2bf(p0.z) | (f2bf(p0.w) << 16);
        va.z = f2bf(p1.x) | (f2bf(p1.y) << 16);
        va.w = f2bf(p1.z) | (f2bf(p1.w) << 16);
        *(uint4*)(out + i) = va;
    }
}

// ---------------- GEMM 128x256 tile, 8 waves, dbuf glds staging (r12: confirmed
// win — both layers left top-5, wall 454.6 -> 427.7). BN=256 halves A-panel
// re-reads; 3 blocks/CU = 24 waves/CU cover barrier stalls.
// eler_mode 1: block covers heads 2*by, 2*by+1 -> el[m*4+2*by+hh] per half.
// eler_mode 2: single block in y covers all N -> direct store (no atomics).
__global__ __launch_bounds__(512) void gemm_bt(
    const unsigned short* __restrict__ A, const int* __restrict__ flagp,
    const unsigned short* __restrict__ BT,
    void* __restrict__ C, int c_q8,
    int M, int K, int Nc,
    const void* __restrict__ al, const void* __restrict__ ar,
    float* __restrict__ el, float* __restrict__ er, int eler_mode)
{
    __shared__ unsigned short Als[2][128 * 32];
    __shared__ unsigned short Bls[2][256 * 32];
    __shared__ float elp[2][128];
    __shared__ float erp[2][128];
    int isbf = (*flagp != 0);
    int tid  = threadIdx.x;
    int wave = tid >> 6;          // 0..7
    int lane = tid & 63;
    int wr = (wave >> 2) * 64;    // 0,64
    int wc = (wave & 3) * 64;     // 0,64,128,192
    int hh = (wave & 3) >> 1;     // column half 0/1 (local cols 0-127 / 128-255)
    int m0 = blockIdx.x * 128;
    int n0 = blockIdx.y * 256;
    if (tid < 256) { (&elp[0][0])[tid] = 0.f; (&erp[0][0])[tid] = 0.f; }
    f32x4 acc[4][4];
#pragma unroll
    for (int i = 0; i < 4; i++)
#pragma unroll
        for (int j = 0; j < 4; j++) acc[i][j] = (f32x4){0.f, 0.f, 0.f, 0.f};
    int frow = lane & 15;
    int kg = (lane >> 4) * 8;
    // staging geometry: 24 chunks of 16 rows (1KB); chunks 0-7 = A, 8-23 = B.
    // lane i -> row i>>2, col (i&3)*8. wave w stages chunks 3w..3w+2.
    int srow = lane >> 2;
    int scol = (lane & 3) * 8;
    auto STAGE = [&](int buf, int kt) {
#pragma unroll
        for (int q = 0; q < 3; ++q) {
            int chunk = wave * 3 + q;            // 0..23
            if (chunk < 8) {
                int r = chunk * 16 + srow;
                int gm = m0 + r; if (gm >= M) gm = M - 1;   // clamp: dup reads
                glds16(A + (size_t)gm * K + kt + scol, Als[buf] + chunk * 512);
            } else {
                int r = (chunk - 8) * 16 + srow;            // 0..255, Nc mult of 256
                glds16(BT + (size_t)(n0 + r) * K + kt + scol, Bls[buf] + (chunk - 8) * 512);
            }
        }
    };
    int nt = K >> 5;
    int cur = 0;
    STAGE(0, 0);
    __syncthreads();                     // buf0 ready (+ elp/erp zero-init visible)
    for (int t = 0; t < nt; ++t) {
        if (t + 1 < nt) STAGE(cur ^ 1, (t + 1) * 32);   // async prefetch next tile
        bf16x8 af[4], bfr[4];
#pragma unroll
        for (int i = 0; i < 4; i++)
            af[i] = __builtin_bit_cast(bf16x8, *(const uint4*)(Als[cur] + (wr + i * 16 + frow) * 32 + kg));
#pragma unroll
        for (int j = 0; j < 4; j++)
            bfr[j] = __builtin_bit_cast(bf16x8, *(const uint4*)(Bls[cur] + (wc + j * 16 + frow) * 32 + kg));
#pragma unroll
        for (int i = 0; i < 4; i++)
#pragma unroll
            for (int j = 0; j < 4; j++)
                acc[i][j] = __builtin_amdgcn_mfma_f32_16x16x32_bf16(af[i], bfr[j], acc[i][j], 0, 0, 0);
        __syncthreads();
        cur ^= 1;
    }
    // C store. C/D layout: col = lane&15, row = (lane>>4)*4 + reg
    int nb = n0 + wc + frow;
    int mb = m0 + wr + (lane >> 4) * 4;
#pragma unroll
    for (int i = 0; i < 4; i++) {
#pragma unroll
        for (int j = 0; j < 4; j++) {
            int n = nb + j * 16;
#pragma unroll
            for (int r = 0; r < 4; r++) {
                int m = mb + i * 16 + r;
                if (m < M) {
                    if (c_q8)
                        ((unsigned char*)C)[(size_t)m * Nc + n] = (unsigned char)f2q8(acc[i][j][r]);
                    else
                        ((unsigned short*)C)[(size_t)m * Nc + n] = (unsigned short)f2bf(acc[i][j][r]);
                }
            }
        }
    }
    // fused el/er: per-row dot with al/ar over this wave's 64 cols, accumulated
    // per column-half so layer1 heads stay separate.
    float alv[4], arv[4];
#pragma unroll
    for (int j = 0; j < 4; j++) {
        int c = n0 + wc + frow + j * 16;
        alv[j] = loadf(al, c, isbf);
        arv[j] = loadf(ar, c, isbf);
    }
#pragma unroll
    for (int i = 0; i < 4; i++) {
#pragma unroll
        for (int r = 0; r < 4; r++) {
            float pe = 0.f, pr = 0.f;
#pragma unroll
            for (int j = 0; j < 4; j++) {
                pe += acc[i][j][r] * alv[j];
                pr += acc[i][j][r] * arv[j];
            }
#pragma unroll
            for (int o = 1; o < 16; o <<= 1) {
                pe += __shfl_xor(pe, o);
                pr += __shfl_xor(pr, o);
            }
            if ((lane & 15) == 0) {
                int row = wr + (lane >> 4) * 4 + i * 16 + r;
                atomicAdd(&elp[hh][row], pe);
                atomicAdd(&erp[hh][row], pr);
            }
        }
    }
    __syncthreads();
    if (tid < 256) {
        int row = tid & 127, half = tid >> 7;
        int m = m0 + row;
        if (m < M) {
            if (eler_mode == 1) {
                el[m * 4 + blockIdx.y * 2 + half] = elp[half][row];
                er[m * 4 + blockIdx.y * 2 + half] = erp[half][row];
            } else if (half == 0) {
                el[m] = elp[0][row] + elp[1][row];
                er[m] = erp[0][row] + erp[1][row];
            }
        }
    }
}

// ---------------- transpose external weight [R,C] -> internal bf16 [C,R]
__global__ void transpose_k(const void* __restrict__ in, const int* __restrict__ flagp,
                            unsigned short* __restrict__ out, int R, int C) {
    int isbf = (*flagp != 0);
    int idx = blockIdx.x * blockDim.x + threadIdx.x;
    if (idx < R * C) {
        int i = idx / C, j = idx - i * C;
        unsigned short v = isbf ? ((const unsigned short*)in)[idx]
                                : (unsigned short)f2bf(((const float*)in)[idx]);
        out[j * R + i] = v;
    }
}

// ---------------- deterministic two-level CSR sort ----------------
__global__ __launch_bounds__(256) void binA_k(
    const int* __restrict__ dst1, const int* __restrict__ dst2,
    int* __restrict__ hist)
{
    __shared__ int lh[NB];
    int t = threadIdx.x, w = blockIdx.x;
    for (int b = t; b < NB; b += 256) lh[b] = 0;
    __syncthreads();
    int base = w * CH;
    for (int k = 0; k < CH; k += 256) {
        int i = base + k + t;
        if (i < 2 * EE) {
            int d, lay;
            if (i < EE) { d = dst1[i]; lay = 0; }
            else        { d = dst2[i - EE]; lay = 1; }
            d = ((unsigned)d < (unsigned)NN) ? d : 0;
            atomicAdd(&lh[lay * NB1 + (d >> 6)], 1);
        }
    }
    __syncthreads();
    for (int b = t; b < NB; b += 256) hist[b * WGN + w] = lh[b];
}
__global__ void scan_a(int* __restrict__ hist, int* __restrict__ bsum) {
    __shared__ int sdata[256];
    int t = threadIdx.x;
    int g = blockIdx.x * 256 + t;
    int v = (g < TOT) ? hist[g] : 0;
    sdata[t] = v;
    __syncthreads();
    for (int o = 1; o < 256; o <<= 1) {
        int x = (t >= o) ? sdata[t - o] : 0;
        __syncthreads();
        sdata[t] += x;
        __syncthreads();
    }
    if (g < TOT) hist[g] = sdata[t] - v;
    if (t == 255) bsum[blockIdx.x] = sdata[255];
}
__global__ void scan_b(const int* __restrict__ bsum, int* __restrict__ boff) {
    __shared__ int sdata[1024];
    int t = threadIdx.x;           // 1024 threads
    int v = (t < SB2) ? bsum[t] : 0;
    sdata[t] = v;
    __syncthreads();
    for (int o = 1; o < 1024; o <<= 1) {
        int x = (t >= o) ? sdata[t - o] : 0;
        __syncthreads();
        sdata[t] += x;
        __syncthreads();
    }
    boff[t] = sdata[t] - v;
}
__global__ void scan_c(int* __restrict__ hist, const int* __restrict__ boff) {
    int g = blockIdx.x * 256 + threadIdx.x;
    if (g < TOT) hist[g] += boff[blockIdx.x];
}
__global__ __launch_bounds__(256) void binC_k(
    const int* __restrict__ src1, const int* __restrict__ dst1,
    const int* __restrict__ src2, const int* __restrict__ dst2,
    const int* __restrict__ base_g, unsigned int* __restrict__ bucketed)
{
    __shared__ int cur[NB];
    int t = threadIdx.x, w = blockIdx.x;
    for (int b = t; b < NB; b += 256) cur[b] = base_g[b * WGN + w];
    __syncthreads();
    int base = w * CH;
    for (int k = 0; k < CH; k += 256) {
        int i = base + k + t;
        if (i < 2 * EE) {
            int d, s, lay;
            if (i < EE) { d = dst1[i]; s = src1[i]; lay = 0; }
            else        { d = dst2[i - EE]; s = src2[i - EE]; lay = 1; }
            d = ((unsigned)d < (unsigned)NN) ? d : 0;
            s = ((unsigned)s < (unsigned)NN) ? s : 0;
            int b = lay * NB1 + (d >> 6);
            int p = atomicAdd(&cur[b], 1);
            bucketed[p] = (unsigned)s | ((unsigned)(d & 63) << 16);
        }
    }
}
// binD: csr packs s (low16) | d (high16) — both < 65536. d is needed by the
// edge-weight precompute kernels (wgt1_k/wgt2_k) which run per CSR position.
__global__ __launch_bounds__(256) void binD_k(
    const int* __restrict__ base_g, const unsigned int* __restrict__ bucketed,
    int* __restrict__ csr, int* __restrict__ row_ptr)
{
    __shared__ int cnt[64];
    __shared__ int off[64];
    __shared__ int cur[64];
    int b = blockIdx.x, t = threadIdx.x;
    int s = base_g[b * WGN];
    int e = (b + 1 < NB) ? base_g[(b + 1) * WGN] : (2 * EE);
    int lay = (b >= NB1) ? 1 : 0;
    int b0 = b - lay * NB1;
    if (t < 64) cnt[t] = 0;
    __syncthreads();
    for (int i = s + t; i < e; i += 256)
        atomicAdd(&cnt[bucketed[i] >> 16], 1);
    __syncthreads();
    if (t == 0) {
        int run = s;
        for (int j = 0; j < 64; j++) { off[j] = run; run += cnt[j]; }
    }
    __syncthreads();
    if (t < 64) {
        int node = b0 * 64 + t;
        if (node < NN) row_ptr[lay * NN + node] = off[t];
        cur[t] = off[t];
    }
    __syncthreads();
    for (int i = s + t; i < e; i += 256) {
        unsigned v = bucketed[i];
        int p = atomicAdd(&cur[v >> 16], 1);
        unsigned node = (unsigned)(b0 * 64) + (v >> 16);
        csr[p] = (int)((v & 0xFFFFu) | (node << 16));
    }
    if (b == NB - 1 && t == 0) row_ptr[2 * NN] = e;
}

// ---------------- edge-weight precompute (one thread per edge x head).
// Replaces the 16x-redundant per-lane exp(leaky(el+er)) chain inside agg kernels.
__global__ __launch_bounds__(256) void wgt1_k(
    const int* __restrict__ csr, const float* __restrict__ el,
    const float* __restrict__ er, float* __restrict__ w)
{
    int idx = blockIdx.x * 256 + threadIdx.x;
    if (idx >= EE * 4) return;
    int p = idx >> 2, h = idx & 3;
    unsigned c = (unsigned)csr[p];
    int s = (int)(c & 0xFFFFu);
    int d = (int)(c >> 16);
    s = ((unsigned)s < (unsigned)NN) ? s : 0;
    d = ((unsigned)d < (unsigned)NN) ? d : 0;
    float ev = el[s * 4 + h] + er[d * 4 + h];
    ev = (ev > 0.f) ? ev : 0.2f * ev;
    w[idx] = __expf(fminf(ev, 80.f));
}
__global__ __launch_bounds__(256) void wgt2_k(
    const int* __restrict__ csr, const float* __restrict__ el,
    const float* __restrict__ er, float* __restrict__ w)
{
    int p = blockIdx.x * 256 + threadIdx.x;
    if (p >= EE) return;
    unsigned c = (unsigned)csr[EE + p];
    int s = (int)(c & 0xFFFFu);
    int d = (int)(c >> 16);
    s = ((unsigned)s < (unsigned)NN) ? s : 0;
    d = ((unsigned)d < (unsigned)NN) ? d : 0;
    float ev = el[s] + er[d];
    ev = (ev > 0.f) ? ev : 0.2f * ev;
    w[p] = __expf(fminf(ev, 80.f));
}

// ---------------- layer1 aggregation: 8-deep gather pipeline + SOFTWARE-
// PIPELINED INDEX STREAM (r14: each 8-group began with 8 dependent csr loads —
// ~200cy L2 latency exposed at every loop top; now group g+1's indices load
// during group g's gathers/compute). Packed f32x2 acc kept. Clamps + size_t
// addressing r10-exact.
__global__ __launch_bounds__(256) void agg1_k(
    const unsigned char* __restrict__ h1,
    const float* __restrict__ wgt,
    const int* __restrict__ row_ptr, const int* __restrict__ csr,
    unsigned short* __restrict__ x2)
{
    int wv = (blockIdx.x * blockDim.x + threadIdx.x) >> 6;
    int lane = threadIdx.x & 63;
    if (wv >= NN) return;
    int h = lane >> 4;
    int e0 = row_ptr[wv], e1 = row_ptr[wv + 1];
    float l = 0.f;
    f32x2 acc[4];
#pragma unroll
    for (int j = 0; j < 4; j++) acc[j] = (f32x2){0.f, 0.f};
    int n8 = (e1 - e0) >> 3;
    int cv[8];
    if (n8 > 0) {
#pragma unroll
        for (int q = 0; q < 8; q++) cv[q] = csr[e0 + q];
    }
    for (int g = 0; g < n8; ++g) {
        int base = e0 + (g << 3);
        int sv[8];
#pragma unroll
        for (int q = 0; q < 8; q++) {
            int s = cv[q] & 0xFFFF;
            sv[q] = ((unsigned)s < (unsigned)NN) ? s : 0;
        }
        uint2 pv[8];
#pragma unroll
        for (int q = 0; q < 8; q++)
            pv[q] = *(const uint2*)(h1 + (size_t)sv[q] * HD1 + lane * 8);
        if (g + 1 < n8) {                    // prefetch next group's indices
#pragma unroll
            for (int q = 0; q < 8; q++) cv[q] = csr[base + 8 + q];
        }
        float wvv[8];
#pragma unroll
        for (int q = 0; q < 8; q++) wvv[q] = wgt[(base + q) * 4 + h];
        l += ((wvv[0] + wvv[1]) + (wvv[2] + wvv[3]))
           + ((wvv[4] + wvv[5]) + (wvv[6] + wvv[7]));
#pragma unroll
        for (int q = 0; q < 8; q++) {
            f32x2 f[4];
            unpack8_u8_v2(pv[q], f);
#pragma unroll
            for (int j = 0; j < 4; j++) acc[j] += wvv[q] * f[j];
        }
    }
    int e = e0 + (n8 << 3);
    if (e + 3 < e1) {                  // one 4-deep step
        int s0 = csr[e] & 0xFFFF,     s1 = csr[e + 1] & 0xFFFF;
        int s2 = csr[e + 2] & 0xFFFF, s3 = csr[e + 3] & 0xFFFF;
        s0 = ((unsigned)s0 < (unsigned)NN) ? s0 : 0;
        s1 = ((unsigned)s1 < (unsigned)NN) ? s1 : 0;
        s2 = ((unsigned)s2 < (unsigned)NN) ? s2 : 0;
        s3 = ((unsigned)s3 < (unsigned)NN) ? s3 : 0;
        uint2 p0 = *(const uint2*)(h1 + (size_t)s0 * HD1 + lane * 8);
        uint2 p1 = *(const uint2*)(h1 + (size_t)s1 * HD1 + lane * 8);
        uint2 p2 = *(const uint2*)(h1 + (size_t)s2 * HD1 + lane * 8);
        uint2 p3 = *(const uint2*)(h1 + (size_t)s3 * HD1 + lane * 8);
        float w0 = wgt[e * 4 + h];
        float w1 = wgt[(e + 1) * 4 + h];
        float w2 = wgt[(e + 2) * 4 + h];
        float w3 = wgt[(e + 3) * 4 + h];
        f32x2 f0[4], f1[4], f2[4], f3[4];
        unpack8_u8_v2(p0, f0);
        unpack8_u8_v2(p1, f1);
        unpack8_u8_v2(p2, f2);
        unpack8_u8_v2(p3, f3);
        l += (w0 + w1) + (w2 + w3);
#pragma unroll
        for (int j = 0; j < 4; j++)
            acc[j] += (w0 * f0[j] + w1 * f1[j]) + (w2 * f2[j] + w3 * f3[j]);
        e += 4;
    }
    for (; e < e1; ++e) {
        int s = csr[e] & 0xFFFF;
        s = ((unsigned)s < (unsigned)NN) ? s : 0;
        float w0 = wgt[e * 4 + h];
        l += w0;
        f32x2 hf[4];
        unpack8_u8_v2(*(const uint2*)(h1 + (size_t)s * HD1 + lane * 8), hf);
#pragma unroll
        for (int j = 0; j < 4; j++) acc[j] += w0 * hf[j];
    }
    float inv = 1.f / (l + 1e-9f);
    float sc = Q_INV * inv;          // fold Q_INV out of the inner loop
    float bias = 128.f * l;          // uint8 bias correction
    unsigned int o[4];
#pragma unroll
    for (int j = 0; j < 4; j++) {
        float v0 = (acc[j].x - bias) * sc;
        float v1 = (acc[j].y - bias) * sc;
        v0 = (v0 > 0.f) ? v0 : (__expf(v0) - 1.f);   // ELU
        v1 = (v1 > 0.f) ? v1 : (__expf(v1) - 1.f);
        o[j] = f2bf(v0) | (f2bf(v1) << 16);
    }
    *(uint4*)(x2 + (size_t)wv * HD1 + lane * 8) = make_uint4(o[0], o[1], o[2], o[3]);
}

// ---------------- layer2 aggregation -> final output (dtype per flag), h2 bf16,
// precomputed weights, 8-deep gather pipeline + pipelined index stream
__global__ __launch_bounds__(256) void agg2_k(
    const unsigned short* __restrict__ h2,
    const float* __restrict__ wgt,
    const int* __restrict__ row_ptr, const int* __restrict__ csr,
    void* __restrict__ outv, const int* __restrict__ flagp)
{
    int isbf = (*flagp != 0);
    int wv = (blockIdx.x * blockDim.x + threadIdx.x) >> 6;
    int lane = threadIdx.x & 63;
    if (wv >= NN) return;
    int e0 = row_ptr[NN + wv], e1 = row_ptr[NN + wv + 1];
    float l = 0.f;
    f32x2 a01 = (f32x2){0.f, 0.f};
    f32x2 a23 = (f32x2){0.f, 0.f};
    int n8 = (e1 - e0) >> 3;
    int cv[8];
    if (n8 > 0) {
#pragma unroll
        for (int q = 0; q < 8; q++) cv[q] = csr[e0 + q];
    }
    for (int g = 0; g < n8; ++g) {
        int base = e0 + (g << 3);
        int sv[8];
#pragma unroll
        for (int q = 0; q < 8; q++) {
            int s = cv[q] & 0xFFFF;
            sv[q] = ((unsigned)s < (unsigned)NN) ? s : 0;
        }
        uint2 tv[8];
#pragma unroll
        for (int q = 0; q < 8; q++)
            tv[q] = *(const uint2*)(h2 + (size_t)sv[q] * D2C + lane * 4);
        if (g + 1 < n8) {                    // prefetch next group's indices
#pragma unroll
            for (int q = 0; q < 8; q++) cv[q] = csr[base + 8 + q];
        }
        float wvv[8];
#pragma unroll
        for (int q = 0; q < 8; q++) wvv[q] = wgt[base + q - EE];
        l += ((wvv[0] + wvv[1]) + (wvv[2] + wvv[3]))
           + ((wvv[4] + wvv[5]) + (wvv[6] + wvv[7]));
#pragma unroll
        for (int q = 0; q < 8; q++) {
            a01 += wvv[q] * (f32x2){bf2f(tv[q].x & 0xffffu), bf2f(tv[q].x >> 16)};
            a23 += wvv[q] * (f32x2){bf2f(tv[q].y & 0xffffu), bf2f(tv[q].y >> 16)};
        }
    }
    int e = e0 + (n8 << 3);
    if (e + 3 < e1) {
        int s0 = csr[e] & 0xFFFF,     s1 = csr[e + 1] & 0xFFFF;
        int s2 = csr[e + 2] & 0xFFFF, s3 = csr[e + 3] & 0xFFFF;
        s0 = ((unsigned)s0 < (unsigned)NN) ? s0 : 0;
        s1 = ((unsigned)s1 < (unsigned)NN) ? s1 : 0;
        s2 = ((unsigned)s2 < (unsigned)NN) ? s2 : 0;
        s3 = ((unsigned)s3 < (unsigned)NN) ? s3 : 0;
        uint2 t0 = *(const uint2*)(h2 + (size_t)s0 * D2C + lane * 4);
        uint2 t1 = *(const uint2*)(h2 + (size_t)s1 * D2C + lane * 4);
        uint2 t2 = *(const uint2*)(h2 + (size_t)s2 * D2C + lane * 4);
        uint2 t3 = *(const uint2*)(h2 + (size_t)s3 * D2C + lane * 4);
        float w0 = wgt[e - EE];
        float w1 = wgt[e + 1 - EE];
        float w2 = wgt[e + 2 - EE];
        float w3 = wgt[e + 3 - EE];
        l += (w0 + w1) + (w2 + w3);
        a01 += (w0 * (f32x2){bf2f(t0.x & 0xffffu), bf2f(t0.x >> 16)}
              + w1 * (f32x2){bf2f(t1.x & 0xffffu), bf2f(t1.x >> 16)})
             + (w2 * (f32x2){bf2f(t2.x & 0xffffu), bf2f(t2.x >> 16)}
              + w3 * (f32x2){bf2f(t3.x & 0xffffu), bf2f(t3.x >> 16)});
        a23 += (w0 * (f32x2){bf2f(t0.y & 0xffffu), bf2f(t0.y >> 16)}
              + w1 * (f32x2){bf2f(t1.y & 0xffffu), bf2f(t1.y >> 16)})
             + (w2 * (f32x2){bf2f(t2.y & 0xffffu), bf2f(t2.y >> 16)}
              + w3 * (f32x2){bf2f(t3.y & 0xffffu), bf2f(t3.y >> 16)});
        e += 4;
    }
    for (; e < e1; ++e) {
        int s = csr[e] & 0xFFFF;
        s = ((unsigned)s < (unsigned)NN) ? s : 0;
        float w0 = wgt[e - EE];
        l += w0;
        uint2 t = *(const uint2*)(h2 + (size_t)s * D2C + lane * 4);
        a01 += w0 * (f32x2){bf2f(t.x & 0xffffu), bf2f(t.x >> 16)};
        a23 += w0 * (f32x2){bf2f(t.y & 0xffffu), bf2f(t.y >> 16)};
    }
    float inv = 1.f / (l + 1e-9f);
    float v0 = a01.x * inv, v1 = a01.y * inv, v2 = a23.x * inv, v3 = a23.y * inv;
    if (isbf) {
        uint2 o;
        o.x = f2bf(v0) | (f2bf(v1) << 16);
        o.y = f2bf(v2) | (f2bf(v3) << 16);
        *(uint2*)((unsigned short*)outv + (size_t)wv * D2C + lane * 4) = o;
    } else {
        f32x4 o = (f32x4){v0, v1, v2, v3};
        *(f32x4*)((float*)outv + (size_t)wv * D2C + lane * 4) = o;
    }
}

extern "C" void kernel_launch(void* const* d_in, const int* in_sizes, int n_in,
                              void* d_out, int out_size, void* d_ws, size_t ws_size,
                              hipStream_t stream) {
    const void* feat = d_in[0];
    const int* src1 = (const int*)d_in[1];
    const int* dst1 = (const int*)d_in[2];
    const int* src2 = (const int*)d_in[3];
    const int* dst2 = (const int*)d_in[4];
    const void* W1  = d_in[5];
    const void* al1 = d_in[6];
    const void* ar1 = d_in[7];
    const void* W2  = d_in[8];
    const void* al2 = d_in[9];
    const void* ar2 = d_in[10];

    uint8_t* w = (uint8_t*)d_ws;
    auto alloc = [&](size_t bytes) -> void* {
        void* p = (void*)w;
        w += (bytes + 255) & ~(size_t)255;
        return p;
    };
    int* flag    = (int*)alloc(256);
    float* el    = (float*)alloc((size_t)NN * 4 * 4);
    float* er    = (float*)alloc((size_t)NN * 4 * 4);
    unsigned short* W1T = (unsigned short*)alloc((size_t)IND * HD1 * 2);
    unsigned short* W2T = (unsigned short*)alloc((size_t)HD1 * D2C * 2);
    int* hist    = (int*)alloc((size_t)TOT * 4);
    int* bsum    = (int*)alloc(1024 * 4);
    int* boff    = (int*)alloc(1024 * 4);
    unsigned int* bucketed = (unsigned int*)alloc((size_t)2 * EE * 4);
    int* csr     = (int*)alloc((size_t)2 * EE * 4);
    int* row_ptr = (int*)alloc((size_t)(2 * NN + 1) * 4);
    unsigned char* h1 = (unsigned char*)alloc((size_t)NN * HD1);  // int8: 1 B/elem
    unsigned short* x2 = (unsigned short*)alloc((size_t)NN * HD1 * 2);
    float* w1e   = (float*)alloc((size_t)EE * 4 * 4);   // layer1 edge weights (12.8 MB)
    unsigned short* h2 = (unsigned short*)h1;   // bf16 [NN,256] = same footprint
    // featb (bf16 feat) aliases x2: dead after gemm1 reads it, before agg1 writes x2
    unsigned short* featb = x2;
    // w2e aliases bucketed: dead after binD, wgt2_k runs after gemm2
    float* w2e   = (float*)bucketed;

    probe_k<<<1, 256, 0, stream>>>((const unsigned int*)feat, flag);
    convert_k<<<(NN * IND / 8 + 255) / 256, 256, 0, stream>>>(feat, flag, featb);
    transpose_k<<<(IND * HD1 + 255) / 256, 256, 0, stream>>>(W1, flag, W1T, IND, HD1);
    transpose_k<<<(HD1 * D2C + 255) / 256, 256, 0, stream>>>(W2, flag, W2T, HD1, D2C);

    // ---- deterministic two-level CSR build (both layers)
    binA_k<<<WGN, 256, 0, stream>>>(dst1, dst2, hist);
    scan_a<<<SB2, 256, 0, stream>>>(hist, bsum);
    scan_b<<<1, 1024, 0, stream>>>(bsum, boff);
    scan_c<<<SB2, 256, 0, stream>>>(hist, boff);
    binC_k<<<WGN, 256, 0, stream>>>(src1, dst1, src2, dst2, hist, bucketed);
    binD_k<<<NB, 256, 0, stream>>>(hist, bucketed, csr, row_ptr);

    // ---- layer 1 (128x256-tile dbuf glds GEMM; fused el/er per head-half)
    gemm_bt<<<dim3((NN + 127) / 128, HD1 / 256), 512, 0, stream>>>(
        featb, flag, W1T, h1, 1, NN, IND, HD1, al1, ar1, el, er, 1);
    wgt1_k<<<(EE * 4 + 255) / 256, 256, 0, stream>>>(csr, el, er, w1e);
    agg1_k<<<(NN + 3) / 4, 256, 0, stream>>>(h1, w1e, row_ptr, csr, x2);

    // ---- layer 2 (single y-block covers all N; el/er direct store)
    gemm_bt<<<dim3((NN + 127) / 128, D2C / 256), 512, 0, stream>>>(
        x2, flag, W2T, (void*)h2, 0, NN, HD1, D2C, al2, ar2, el, er, 2);
    wgt2_k<<<(EE + 255) / 256, 256, 0, stream>>>(csr, el, er, w2e);
    agg2_k<<<(NN + 3) / 4, 256, 0, stream>>>(h2, w2e, row_ptr, csr, d_out, flag);
}

// Round 16
// 419.783 us; speedup vs baseline: 1.0171x; 1.0171x over previous
//
#include <hip/hip_runtime.h>
#include <stdint.h>

#define NN 50000
#define EE 800000
#define IND 256
#define HD1 512   // layer1 concat width (4 heads x 128)
#define D2C 256   // layer2 width

// ---- two-level CSR sort geometry ----
#define NB1 782                 // buckets per layer (64 nodes each)
#define NB  (2 * NB1)           // 1564 buckets total
#define CH  16384               // edges per binning workgroup
#define WGN ((2 * EE + CH - 1) / CH)   // 98 workgroups
#define TOT (NB * WGN)          // 153272 hist entries
#define SB2 ((TOT + 255) / 256) // 599 scan blocks

// int8 fixed-point codec for h1 (values ~N(0,1); range +-6 never clips in practice)
// Stored BIASED (q+128) so decode is v_cvt_f32_ubyte0..3 (1 op/elem, not bfe+cvt).
// Bias correction folds into epilogue: sum w*(q-128)*Q_INV = (sum w*q - 128*l)*Q_INV.
#define Q_SCALE 21.166666f        // 127/6
#define Q_INV   0.047244094f      // 6/127

typedef float f32x4 __attribute__((ext_vector_type(4)));
typedef float f32x2 __attribute__((ext_vector_type(2)));
typedef __bf16 bf16x8 __attribute__((ext_vector_type(8)));

__device__ inline float bf2f(unsigned int u) {
    union { unsigned int i; float f; } c; c.i = u << 16; return c.f;
}
__device__ inline unsigned int f2bf(float f) {
    union { float f; unsigned int i; } c; c.f = f;
    unsigned int x = c.i;
    return (x + 0x7FFFu + ((x >> 16) & 1u)) >> 16;  // RNE
}
__device__ inline float loadf(const void* p, int idx, int isbf) {
    return isbf ? bf2f(((const unsigned short*)p)[idx]) : ((const float*)p)[idx];
}
// encode float -> biased uint8 byte (round-nearest, clamp +-127, +128 bias)
__device__ inline unsigned int f2q8(float v) {
    float t = fminf(fmaxf(v * Q_SCALE, -127.f), 127.f);
    int q = (int)rintf(t) + 128;
    return (unsigned int)q & 0xFFu;
}
// decode 8 biased-uint8 bytes -> 4x f32x2 (v_cvt_f32_ubyte; pairs feed pk-FMA)
__device__ inline void unpack8_u8_v2(uint2 q, f32x2* o) {
    o[0] = (f32x2){(float)(q.x & 0xFFu),         (float)((q.x >> 8) & 0xFFu)};
    o[1] = (f32x2){(float)((q.x >> 16) & 0xFFu), (float)(q.x >> 24)};
    o[2] = (f32x2){(float)(q.y & 0xFFu),         (float)((q.y >> 8) & 0xFFu)};
    o[3] = (f32x2){(float)((q.y >> 16) & 0xFFu), (float)(q.y >> 24)};
}
// async global->LDS 16B per lane: dest = lds_base + lane*16 (wave-uniform base)
__device__ inline void glds16(const unsigned short* g, unsigned short* lds_base) {
    __builtin_amdgcn_global_load_lds(
        (const __attribute__((address_space(1))) void*)g,
        (__attribute__((address_space(3))) void*)lds_base, 16, 0, 0);
}

// ---------------- dtype probe: external float tensors bf16 (flag=1) or fp32 (flag=0)
__global__ void probe_k(const unsigned int* __restrict__ w, int* __restrict__ flag) {
    __shared__ int red[256];
    int t = threadIdx.x;
    int ok = 0;
    for (int i = t; i < 4096; i += 256) {
        unsigned int v = w[i];
        unsigned int e0 = (v >> 7) & 0xffu;
        unsigned int e1 = (v >> 23) & 0xffu;
        ok += (e0 <= 133u) + (e1 <= 133u);
    }
    red[t] = ok;
    __syncthreads();
    for (int s = 128; s > 0; s >>= 1) {
        if (t < s) red[t] += red[t + s];
        __syncthreads();
    }
    if (t == 0) *flag = (red[0] >= 7782) ? 1 : 0;
}

// ---------------- feat -> bf16 (one-time conversion; copy if already bf16)
__global__ __launch_bounds__(256) void convert_k(
    const void* __restrict__ in, const int* __restrict__ flagp,
    unsigned short* __restrict__ out)
{
    int isbf = (*flagp != 0);
    size_t i = ((size_t)blockIdx.x * 256 + threadIdx.x) * 8;
    if (i >= (size_t)NN * IND) return;
    if (isbf) {
        *(uint4*)(out + i) = *(const uint4*)((const unsigned short*)in + i);
    } else {
        const float* f = (const float*)in + i;
        f32x4 p0 = *(const f32x4*)f;
        f32x4 p1 = *(const f32x4*)(f + 4);
        uint4 va;
        va.x = f2bf(p0.x) | (f2bf(p0.y) << 16);
        va.y = f2bf(p0.z) | (f2bf(p0.w) << 16);
        va.z = f2bf(p1.x) | (f2bf(p1.y) << 16);
        va.w = f2bf(p1.z) | (f2bf(p1.w) << 16);
        *(uint4*)(out + i) = va;
    }
}

// ---------------- GEMM 128x256 tile, 8 waves, dbuf glds staging (r12: confirmed
// win — both layers left top-5, wall 454.6 -> 427.7). BN=256 halves A-panel
// re-reads; 3 blocks/CU = 24 waves/CU cover barrier stalls.
// eler_mode 1: block covers heads 2*by, 2*by+1 -> el[m*4+2*by+hh] per half.
// eler_mode 2: single block in y covers all N -> direct store (no atomics).
__global__ __launch_bounds__(512) void gemm_bt(
    const unsigned short* __restrict__ A, const int* __restrict__ flagp,
    const unsigned short* __restrict__ BT,
    void* __restrict__ C, int c_q8,
    int M, int K, int Nc,
    const void* __restrict__ al, const void* __restrict__ ar,
    float* __restrict__ el, float* __restrict__ er, int eler_mode)
{
    __shared__ unsigned short Als[2][128 * 32];
    __shared__ unsigned short Bls[2][256 * 32];
    __shared__ float elp[2][128];
    __shared__ float erp[2][128];
    int isbf = (*flagp != 0);
    int tid  = threadIdx.x;
    int wave = tid >> 6;          // 0..7
    int lane = tid & 63;
    int wr = (wave >> 2) * 64;    // 0,64
    int wc = (wave & 3) * 64;     // 0,64,128,192
    int hh = (wave & 3) >> 1;     // column half 0/1 (local cols 0-127 / 128-255)
    int m0 = blockIdx.x * 128;
    int n0 = blockIdx.y * 256;
    if (tid < 256) { (&elp[0][0])[tid] = 0.f; (&erp[0][0])[tid] = 0.f; }
    f32x4 acc[4][4];
#pragma unroll
    for (int i = 0; i < 4; i++)
#pragma unroll
        for (int j = 0; j < 4; j++) acc[i][j] = (f32x4){0.f, 0.f, 0.f, 0.f};
    int frow = lane & 15;
    int kg = (lane >> 4) * 8;
    // staging geometry: 24 chunks of 16 rows (1KB); chunks 0-7 = A, 8-23 = B.
    // lane i -> row i>>2, col (i&3)*8. wave w stages chunks 3w..3w+2.
    int srow = lane >> 2;
    int scol = (lane & 3) * 8;
    auto STAGE = [&](int buf, int kt) {
#pragma unroll
        for (int q = 0; q < 3; ++q) {
            int chunk = wave * 3 + q;            // 0..23
            if (chunk < 8) {
                int r = chunk * 16 + srow;
                int gm = m0 + r; if (gm >= M) gm = M - 1;   // clamp: dup reads
                glds16(A + (size_t)gm * K + kt + scol, Als[buf] + chunk * 512);
            } else {
                int r = (chunk - 8) * 16 + srow;            // 0..255, Nc mult of 256
                glds16(BT + (size_t)(n0 + r) * K + kt + scol, Bls[buf] + (chunk - 8) * 512);
            }
        }
    };
    int nt = K >> 5;
    int cur = 0;
    STAGE(0, 0);
    __syncthreads();                     // buf0 ready (+ elp/erp zero-init visible)
    for (int t = 0; t < nt; ++t) {
        if (t + 1 < nt) STAGE(cur ^ 1, (t + 1) * 32);   // async prefetch next tile
        bf16x8 af[4], bfr[4];
#pragma unroll
        for (int i = 0; i < 4; i++)
            af[i] = __builtin_bit_cast(bf16x8, *(const uint4*)(Als[cur] + (wr + i * 16 + frow) * 32 + kg));
#pragma unroll
        for (int j = 0; j < 4; j++)
            bfr[j] = __builtin_bit_cast(bf16x8, *(const uint4*)(Bls[cur] + (wc + j * 16 + frow) * 32 + kg));
#pragma unroll
        for (int i = 0; i < 4; i++)
#pragma unroll
            for (int j = 0; j < 4; j++)
                acc[i][j] = __builtin_amdgcn_mfma_f32_16x16x32_bf16(af[i], bfr[j], acc[i][j], 0, 0, 0);
        __syncthreads();
        cur ^= 1;
    }
    // C store. C/D layout: col = lane&15, row = (lane>>4)*4 + reg
    int nb = n0 + wc + frow;
    int mb = m0 + wr + (lane >> 4) * 4;
#pragma unroll
    for (int i = 0; i < 4; i++) {
#pragma unroll
        for (int j = 0; j < 4; j++) {
            int n = nb + j * 16;
#pragma unroll
            for (int r = 0; r < 4; r++) {
                int m = mb + i * 16 + r;
                if (m < M) {
                    if (c_q8)
                        ((unsigned char*)C)[(size_t)m * Nc + n] = (unsigned char)f2q8(acc[i][j][r]);
                    else
                        ((unsigned short*)C)[(size_t)m * Nc + n] = (unsigned short)f2bf(acc[i][j][r]);
                }
            }
        }
    }
    // fused el/er: per-row dot with al/ar over this wave's 64 cols, accumulated
    // per column-half so layer1 heads stay separate.
    float alv[4], arv[4];
#pragma unroll
    for (int j = 0; j < 4; j++) {
        int c = n0 + wc + frow + j * 16;
        alv[j] = loadf(al, c, isbf);
        arv[j] = loadf(ar, c, isbf);
    }
#pragma unroll
    for (int i = 0; i < 4; i++) {
#pragma unroll
        for (int r = 0; r < 4; r++) {
            float pe = 0.f, pr = 0.f;
#pragma unroll
            for (int j = 0; j < 4; j++) {
                pe += acc[i][j][r] * alv[j];
                pr += acc[i][j][r] * arv[j];
            }
#pragma unroll
            for (int o = 1; o < 16; o <<= 1) {
                pe += __shfl_xor(pe, o);
                pr += __shfl_xor(pr, o);
            }
            if ((lane & 15) == 0) {
                int row = wr + (lane >> 4) * 4 + i * 16 + r;
                atomicAdd(&elp[hh][row], pe);
                atomicAdd(&erp[hh][row], pr);
            }
        }
    }
    __syncthreads();
    if (tid < 256) {
        int row = tid & 127, half = tid >> 7;
        int m = m0 + row;
        if (m < M) {
            if (eler_mode == 1) {
                el[m * 4 + blockIdx.y * 2 + half] = elp[half][row];
                er[m * 4 + blockIdx.y * 2 + half] = erp[half][row];
            } else if (half == 0) {
                el[m] = elp[0][row] + elp[1][row];
                er[m] = erp[0][row] + erp[1][row];
            }
        }
    }
}

// ---------------- transpose external weight [R,C] -> internal bf16 [C,R]
__global__ void transpose_k(const void* __restrict__ in, const int* __restrict__ flagp,
                            unsigned short* __restrict__ out, int R, int C) {
    int isbf = (*flagp != 0);
    int idx = blockIdx.x * blockDim.x + threadIdx.x;
    if (idx < R * C) {
        int i = idx / C, j = idx - i * C;
        unsigned short v = isbf ? ((const unsigned short*)in)[idx]
                                : (unsigned short)f2bf(((const float*)in)[idx]);
        out[j * R + i] = v;
    }
}

// ---------------- deterministic two-level CSR sort ----------------
__global__ __launch_bounds__(256) void binA_k(
    const int* __restrict__ dst1, const int* __restrict__ dst2,
    int* __restrict__ hist)
{
    __shared__ int lh[NB];
    int t = threadIdx.x, w = blockIdx.x;
    for (int b = t; b < NB; b += 256) lh[b] = 0;
    __syncthreads();
    int base = w * CH;
    for (int k = 0; k < CH; k += 256) {
        int i = base + k + t;
        if (i < 2 * EE) {
            int d, lay;
            if (i < EE) { d = dst1[i]; lay = 0; }
            else        { d = dst2[i - EE]; lay = 1; }
            d = ((unsigned)d < (unsigned)NN) ? d : 0;
            atomicAdd(&lh[lay * NB1 + (d >> 6)], 1);
        }
    }
    __syncthreads();
    for (int b = t; b < NB; b += 256) hist[b * WGN + w] = lh[b];
}
__global__ void scan_a(int* __restrict__ hist, int* __restrict__ bsum) {
    __shared__ int sdata[256];
    int t = threadIdx.x;
    int g = blockIdx.x * 256 + t;
    int v = (g < TOT) ? hist[g] : 0;
    sdata[t] = v;
    __syncthreads();
    for (int o = 1; o < 256; o <<= 1) {
        int x = (t >= o) ? sdata[t - o] : 0;
        __syncthreads();
        sdata[t] += x;
        __syncthreads();
    }
    if (g < TOT) hist[g] = sdata[t] - v;
    if (t == 255) bsum[blockIdx.x] = sdata[255];
}
__global__ void scan_b(const int* __restrict__ bsum, int* __restrict__ boff) {
    __shared__ int sdata[1024];
    int t = threadIdx.x;           // 1024 threads
    int v = (t < SB2) ? bsum[t] : 0;
    sdata[t] = v;
    __syncthreads();
    for (int o = 1; o < 1024; o <<= 1) {
        int x = (t >= o) ? sdata[t - o] : 0;
        __syncthreads();
        sdata[t] += x;
        __syncthreads();
    }
    boff[t] = sdata[t] - v;
}
__global__ void scan_c(int* __restrict__ hist, const int* __restrict__ boff) {
    int g = blockIdx.x * 256 + threadIdx.x;
    if (g < TOT) hist[g] += boff[blockIdx.x];
}
__global__ __launch_bounds__(256) void binC_k(
    const int* __restrict__ src1, const int* __restrict__ dst1,
    const int* __restrict__ src2, const int* __restrict__ dst2,
    const int* __restrict__ base_g, unsigned int* __restrict__ bucketed)
{
    __shared__ int cur[NB];
    int t = threadIdx.x, w = blockIdx.x;
    for (int b = t; b < NB; b += 256) cur[b] = base_g[b * WGN + w];
    __syncthreads();
    int base = w * CH;
    for (int k = 0; k < CH; k += 256) {
        int i = base + k + t;
        if (i < 2 * EE) {
            int d, s, lay;
            if (i < EE) { d = dst1[i]; s = src1[i]; lay = 0; }
            else        { d = dst2[i - EE]; s = src2[i - EE]; lay = 1; }
            d = ((unsigned)d < (unsigned)NN) ? d : 0;
            s = ((unsigned)s < (unsigned)NN) ? s : 0;
            int b = lay * NB1 + (d >> 6);
            int p = atomicAdd(&cur[b], 1);
            bucketed[p] = (unsigned)s | ((unsigned)(d & 63) << 16);
        }
    }
}
// binD: csr packs s (low16) | d (high16) — both < 65536. d is needed by the
// edge-weight precompute kernels (wgt1_k/wgt2_k) which run per CSR position.
__global__ __launch_bounds__(256) void binD_k(
    const int* __restrict__ base_g, const unsigned int* __restrict__ bucketed,
    int* __restrict__ csr, int* __restrict__ row_ptr)
{
    __shared__ int cnt[64];
    __shared__ int off[64];
    __shared__ int cur[64];
    int b = blockIdx.x, t = threadIdx.x;
    int s = base_g[b * WGN];
    int e = (b + 1 < NB) ? base_g[(b + 1) * WGN] : (2 * EE);
    int lay = (b >= NB1) ? 1 : 0;
    int b0 = b - lay * NB1;
    if (t < 64) cnt[t] = 0;
    __syncthreads();
    for (int i = s + t; i < e; i += 256)
        atomicAdd(&cnt[bucketed[i] >> 16], 1);
    __syncthreads();
    if (t == 0) {
        int run = s;
        for (int j = 0; j < 64; j++) { off[j] = run; run += cnt[j]; }
    }
    __syncthreads();
    if (t < 64) {
        int node = b0 * 64 + t;
        if (node < NN) row_ptr[lay * NN + node] = off[t];
        cur[t] = off[t];
    }
    __syncthreads();
    for (int i = s + t; i < e; i += 256) {
        unsigned v = bucketed[i];
        int p = atomicAdd(&cur[v >> 16], 1);
        unsigned node = (unsigned)(b0 * 64) + (v >> 16);
        csr[p] = (int)((v & 0xFFFFu) | (node << 16));
    }
    if (b == NB - 1 && t == 0) row_ptr[2 * NN] = e;
}

// ---------------- edge-weight precompute (one thread per edge x head).
// Replaces the 16x-redundant per-lane exp(leaky(el+er)) chain inside agg kernels.
__global__ __launch_bounds__(256) void wgt1_k(
    const int* __restrict__ csr, const float* __restrict__ el,
    const float* __restrict__ er, float* __restrict__ w)
{
    int idx = blockIdx.x * 256 + threadIdx.x;
    if (idx >= EE * 4) return;
    int p = idx >> 2, h = idx & 3;
    unsigned c = (unsigned)csr[p];
    int s = (int)(c & 0xFFFFu);
    int d = (int)(c >> 16);
    s = ((unsigned)s < (unsigned)NN) ? s : 0;
    d = ((unsigned)d < (unsigned)NN) ? d : 0;
    float ev = el[s * 4 + h] + er[d * 4 + h];
    ev = (ev > 0.f) ? ev : 0.2f * ev;
    w[idx] = __expf(fminf(ev, 80.f));
}
__global__ __launch_bounds__(256) void wgt2_k(
    const int* __restrict__ csr, const float* __restrict__ el,
    const float* __restrict__ er, float* __restrict__ w)
{
    int p = blockIdx.x * 256 + threadIdx.x;
    if (p >= EE) return;
    unsigned c = (unsigned)csr[EE + p];
    int s = (int)(c & 0xFFFFu);
    int d = (int)(c >> 16);
    s = ((unsigned)s < (unsigned)NN) ? s : 0;
    d = ((unsigned)d < (unsigned)NN) ? d : 0;
    float ev = el[s] + er[d];
    ev = (ev > 0.f) ? ev : 0.2f * ev;
    w[p] = __expf(fminf(ev, 80.f));
}

// ---------------- layer1 aggregation: 8-deep gather pipeline (r14 best: 61.9us,
// wall 421.8). r15's index-stream pipelining REGRESSED (VGPR 32->44, occupancy
// 65->42%) — reverted. Packed f32x2 acc kept. Clamps + size_t r10-exact.
__global__ __launch_bounds__(256) void agg1_k(
    const unsigned char* __restrict__ h1,
    const float* __restrict__ wgt,
    const int* __restrict__ row_ptr, const int* __restrict__ csr,
    unsigned short* __restrict__ x2)
{
    int wv = (blockIdx.x * blockDim.x + threadIdx.x) >> 6;
    int lane = threadIdx.x & 63;
    if (wv >= NN) return;
    int h = lane >> 4;
    int e0 = row_ptr[wv], e1 = row_ptr[wv + 1];
    float l = 0.f;
    f32x2 acc[4];
#pragma unroll
    for (int j = 0; j < 4; j++) acc[j] = (f32x2){0.f, 0.f};
    int e = e0;
    for (; e + 7 < e1; e += 8) {       // eight independent gather chains
        int sv[8];
#pragma unroll
        for (int q = 0; q < 8; q++) {
            int s = csr[e + q] & 0xFFFF;
            sv[q] = ((unsigned)s < (unsigned)NN) ? s : 0;
        }
        uint2 pv[8];
#pragma unroll
        for (int q = 0; q < 8; q++)
            pv[q] = *(const uint2*)(h1 + (size_t)sv[q] * HD1 + lane * 8);
        float wvv[8];
#pragma unroll
        for (int q = 0; q < 8; q++) wvv[q] = wgt[(e + q) * 4 + h];
        l += ((wvv[0] + wvv[1]) + (wvv[2] + wvv[3]))
           + ((wvv[4] + wvv[5]) + (wvv[6] + wvv[7]));
#pragma unroll
        for (int q = 0; q < 8; q++) {
            f32x2 f[4];
            unpack8_u8_v2(pv[q], f);
#pragma unroll
            for (int j = 0; j < 4; j++) acc[j] += wvv[q] * f[j];
        }
    }
    if (e + 3 < e1) {                  // one 4-deep step
        int s0 = csr[e] & 0xFFFF,     s1 = csr[e + 1] & 0xFFFF;
        int s2 = csr[e + 2] & 0xFFFF, s3 = csr[e + 3] & 0xFFFF;
        s0 = ((unsigned)s0 < (unsigned)NN) ? s0 : 0;
        s1 = ((unsigned)s1 < (unsigned)NN) ? s1 : 0;
        s2 = ((unsigned)s2 < (unsigned)NN) ? s2 : 0;
        s3 = ((unsigned)s3 < (unsigned)NN) ? s3 : 0;
        uint2 p0 = *(const uint2*)(h1 + (size_t)s0 * HD1 + lane * 8);
        uint2 p1 = *(const uint2*)(h1 + (size_t)s1 * HD1 + lane * 8);
        uint2 p2 = *(const uint2*)(h1 + (size_t)s2 * HD1 + lane * 8);
        uint2 p3 = *(const uint2*)(h1 + (size_t)s3 * HD1 + lane * 8);
        float w0 = wgt[e * 4 + h];
        float w1 = wgt[(e + 1) * 4 + h];
        float w2 = wgt[(e + 2) * 4 + h];
        float w3 = wgt[(e + 3) * 4 + h];
        f32x2 f0[4], f1[4], f2[4], f3[4];
        unpack8_u8_v2(p0, f0);
        unpack8_u8_v2(p1, f1);
        unpack8_u8_v2(p2, f2);
        unpack8_u8_v2(p3, f3);
        l += (w0 + w1) + (w2 + w3);
#pragma unroll
        for (int j = 0; j < 4; j++)
            acc[j] += (w0 * f0[j] + w1 * f1[j]) + (w2 * f2[j] + w3 * f3[j]);
        e += 4;
    }
    for (; e < e1; ++e) {
        int s = csr[e] & 0xFFFF;
        s = ((unsigned)s < (unsigned)NN) ? s : 0;
        float w0 = wgt[e * 4 + h];
        l += w0;
        f32x2 hf[4];
        unpack8_u8_v2(*(const uint2*)(h1 + (size_t)s * HD1 + lane * 8), hf);
#pragma unroll
        for (int j = 0; j < 4; j++) acc[j] += w0 * hf[j];
    }
    float inv = 1.f / (l + 1e-9f);
    float sc = Q_INV * inv;          // fold Q_INV out of the inner loop
    float bias = 128.f * l;          // uint8 bias correction
    unsigned int o[4];
#pragma unroll
    for (int j = 0; j < 4; j++) {
        float v0 = (acc[j].x - bias) * sc;
        float v1 = (acc[j].y - bias) * sc;
        v0 = (v0 > 0.f) ? v0 : (__expf(v0) - 1.f);   // ELU
        v1 = (v1 > 0.f) ? v1 : (__expf(v1) - 1.f);
        o[j] = f2bf(v0) | (f2bf(v1) << 16);
    }
    *(uint4*)(x2 + (size_t)wv * HD1 + lane * 8) = make_uint4(o[0], o[1], o[2], o[3]);
}

// ---------------- layer2 aggregation -> final output (dtype per flag), h2 bf16,
// precomputed weights, 8-deep gather pipeline + packed-f32 accumulators
__global__ __launch_bounds__(256) void agg2_k(
    const unsigned short* __restrict__ h2,
    const float* __restrict__ wgt,
    const int* __restrict__ row_ptr, const int* __restrict__ csr,
    void* __restrict__ outv, const int* __restrict__ flagp)
{
    int isbf = (*flagp != 0);
    int wv = (blockIdx.x * blockDim.x + threadIdx.x) >> 6;
    int lane = threadIdx.x & 63;
    if (wv >= NN) return;
    int e0 = row_ptr[NN + wv], e1 = row_ptr[NN + wv + 1];
    float l = 0.f;
    f32x2 a01 = (f32x2){0.f, 0.f};
    f32x2 a23 = (f32x2){0.f, 0.f};
    int e = e0;
    for (; e + 7 < e1; e += 8) {
        int sv[8];
#pragma unroll
        for (int q = 0; q < 8; q++) {
            int s = csr[e + q] & 0xFFFF;
            sv[q] = ((unsigned)s < (unsigned)NN) ? s : 0;
        }
        uint2 tv[8];
#pragma unroll
        for (int q = 0; q < 8; q++)
            tv[q] = *(const uint2*)(h2 + (size_t)sv[q] * D2C + lane * 4);
        float wvv[8];
#pragma unroll
        for (int q = 0; q < 8; q++) wvv[q] = wgt[e + q - EE];
        l += ((wvv[0] + wvv[1]) + (wvv[2] + wvv[3]))
           + ((wvv[4] + wvv[5]) + (wvv[6] + wvv[7]));
#pragma unroll
        for (int q = 0; q < 8; q++) {
            a01 += wvv[q] * (f32x2){bf2f(tv[q].x & 0xffffu), bf2f(tv[q].x >> 16)};
            a23 += wvv[q] * (f32x2){bf2f(tv[q].y & 0xffffu), bf2f(tv[q].y >> 16)};
        }
    }
    if (e + 3 < e1) {
        int s0 = csr[e] & 0xFFFF,     s1 = csr[e + 1] & 0xFFFF;
        int s2 = csr[e + 2] & 0xFFFF, s3 = csr[e + 3] & 0xFFFF;
        s0 = ((unsigned)s0 < (unsigned)NN) ? s0 : 0;
        s1 = ((unsigned)s1 < (unsigned)NN) ? s1 : 0;
        s2 = ((unsigned)s2 < (unsigned)NN) ? s2 : 0;
        s3 = ((unsigned)s3 < (unsigned)NN) ? s3 : 0;
        uint2 t0 = *(const uint2*)(h2 + (size_t)s0 * D2C + lane * 4);
        uint2 t1 = *(const uint2*)(h2 + (size_t)s1 * D2C + lane * 4);
        uint2 t2 = *(const uint2*)(h2 + (size_t)s2 * D2C + lane * 4);
        uint2 t3 = *(const uint2*)(h2 + (size_t)s3 * D2C + lane * 4);
        float w0 = wgt[e - EE];
        float w1 = wgt[e + 1 - EE];
        float w2 = wgt[e + 2 - EE];
        float w3 = wgt[e + 3 - EE];
        l += (w0 + w1) + (w2 + w3);
        a01 += (w0 * (f32x2){bf2f(t0.x & 0xffffu), bf2f(t0.x >> 16)}
              + w1 * (f32x2){bf2f(t1.x & 0xffffu), bf2f(t1.x >> 16)})
             + (w2 * (f32x2){bf2f(t2.x & 0xffffu), bf2f(t2.x >> 16)}
              + w3 * (f32x2){bf2f(t3.x & 0xffffu), bf2f(t3.x >> 16)});
        a23 += (w0 * (f32x2){bf2f(t0.y & 0xffffu), bf2f(t0.y >> 16)}
              + w1 * (f32x2){bf2f(t1.y & 0xffffu), bf2f(t1.y >> 16)})
             + (w2 * (f32x2){bf2f(t2.y & 0xffffu), bf2f(t2.y >> 16)}
              + w3 * (f32x2){bf2f(t3.y & 0xffffu), bf2f(t3.y >> 16)});
        e += 4;
    }
    for (; e < e1; ++e) {
        int s = csr[e] & 0xFFFF;
        s = ((unsigned)s < (unsigned)NN) ? s : 0;
        float w0 = wgt[e - EE];
        l += w0;
        uint2 t = *(const uint2*)(h2 + (size_t)s * D2C + lane * 4);
        a01 += w0 * (f32x2){bf2f(t.x & 0xffffu), bf2f(t.x >> 16)};
        a23 += w0 * (f32x2){bf2f(t.y & 0xffffu), bf2f(t.y >> 16)};
    }
    float inv = 1.f / (l + 1e-9f);
    float v0 = a01.x * inv, v1 = a01.y * inv, v2 = a23.x * inv, v3 = a23.y * inv;
    if (isbf) {
        uint2 o;
        o.x = f2bf(v0) | (f2bf(v1) << 16);
        o.y = f2bf(v2) | (f2bf(v3) << 16);
        *(uint2*)((unsigned short*)outv + (size_t)wv * D2C + lane * 4) = o;
    } else {
        f32x4 o = (f32x4){v0, v1, v2, v3};
        *(f32x4*)((float*)outv + (size_t)wv * D2C + lane * 4) = o;
    }
}

extern "C" void kernel_launch(void* const* d_in, const int* in_sizes, int n_in,
                              void* d_out, int out_size, void* d_ws, size_t ws_size,
                              hipStream_t stream) {
    const void* feat = d_in[0];
    const int* src1 = (const int*)d_in[1];
    const int* dst1 = (const int*)d_in[2];
    const int* src2 = (const int*)d_in[3];
    const int* dst2 = (const int*)d_in[4];
    const void* W1  = d_in[5];
    const void* al1 = d_in[6];
    const void* ar1 = d_in[7];
    const void* W2  = d_in[8];
    const void* al2 = d_in[9];
    const void* ar2 = d_in[10];

    uint8_t* w = (uint8_t*)d_ws;
    auto alloc = [&](size_t bytes) -> void* {
        void* p = (void*)w;
        w += (bytes + 255) & ~(size_t)255;
        return p;
    };
    int* flag    = (int*)alloc(256);
    float* el    = (float*)alloc((size_t)NN * 4 * 4);
    float* er    = (float*)alloc((size_t)NN * 4 * 4);
    unsigned short* W1T = (unsigned short*)alloc((size_t)IND * HD1 * 2);
    unsigned short* W2T = (unsigned short*)alloc((size_t)HD1 * D2C * 2);
    int* hist    = (int*)alloc((size_t)TOT * 4);
    int* bsum    = (int*)alloc(1024 * 4);
    int* boff    = (int*)alloc(1024 * 4);
    unsigned int* bucketed = (unsigned int*)alloc((size_t)2 * EE * 4);
    int* csr     = (int*)alloc((size_t)2 * EE * 4);
    int* row_ptr = (int*)alloc((size_t)(2 * NN + 1) * 4);
    unsigned char* h1 = (unsigned char*)alloc((size_t)NN * HD1);  // int8: 1 B/elem
    unsigned short* x2 = (unsigned short*)alloc((size_t)NN * HD1 * 2);
    float* w1e   = (float*)alloc((size_t)EE * 4 * 4);   // layer1 edge weights (12.8 MB)
    unsigned short* h2 = (unsigned short*)h1;   // bf16 [NN,256] = same footprint
    // featb (bf16 feat) aliases x2: dead after gemm1 reads it, before agg1 writes x2
    unsigned short* featb = x2;
    // w2e aliases bucketed: dead after binD, wgt2_k runs after gemm2
    float* w2e   = (float*)bucketed;

    probe_k<<<1, 256, 0, stream>>>((const unsigned int*)feat, flag);
    convert_k<<<(NN * IND / 8 + 255) / 256, 256, 0, stream>>>(feat, flag, featb);
    transpose_k<<<(IND * HD1 + 255) / 256, 256, 0, stream>>>(W1, flag, W1T, IND, HD1);
    transpose_k<<<(HD1 * D2C + 255) / 256, 256, 0, stream>>>(W2, flag, W2T, HD1, D2C);

    // ---- deterministic two-level CSR build (both layers)
    binA_k<<<WGN, 256, 0, stream>>>(dst1, dst2, hist);
    scan_a<<<SB2, 256, 0, stream>>>(hist, bsum);
    scan_b<<<1, 1024, 0, stream>>>(bsum, boff);
    scan_c<<<SB2, 256, 0, stream>>>(hist, boff);
    binC_k<<<WGN, 256, 0, stream>>>(src1, dst1, src2, dst2, hist, bucketed);
    binD_k<<<NB, 256, 0, stream>>>(hist, bucketed, csr, row_ptr);

    // ---- layer 1 (128x256-tile dbuf glds GEMM; fused el/er per head-half)
    gemm_bt<<<dim3((NN + 127) / 128, HD1 / 256), 512, 0, stream>>>(
        featb, flag, W1T, h1, 1, NN, IND, HD1, al1, ar1, el, er, 1);
    wgt1_k<<<(EE * 4 + 255) / 256, 256, 0, stream>>>(csr, el, er, w1e);
    agg1_k<<<(NN + 3) / 4, 256, 0, stream>>>(h1, w1e, row_ptr, csr, x2);

    // ---- layer 2 (single y-block covers all N; el/er direct store)
    gemm_bt<<<dim3((NN + 127) / 128, D2C / 256), 512, 0, stream>>>(
        x2, flag, W2T, (void*)h2, 0, NN, HD1, D2C, al2, ar2, el, er, 2);
    wgt2_k<<<(EE + 255) / 256, 256, 0, stream>>>(csr, el, er, w2e);
    agg2_k<<<(NN + 3) / 4, 256, 0, stream>>>(h2, w2e, row_ptr, csr, d_out, flag);
}